// Round 1
// baseline (5857.532 us; speedup 1.0000x reference)
//
#include <hip/hip_runtime.h>

// ---------------- problem constants ----------------
// S=512 seq, B=64 batch, I=256 in, H=1024 hidden, 4H=4096 gates
// d_in: 0:x  1:W1 2:b1 3:W2 4:b2 5:W3 6:b3 7:W4 8:b4 9:W5 10:b5 11:W6 12:b6 13:W7 14:b7 15:W8 16:b8
// Wx = [W1 W3 W5 W7] (gates f,i,o,cand = input side), Wh = [W2 W4 W6 W8] (hidden side)
// out: h_seq (512,64,1024) fp32, then h_final (64,1024), c_final (64,1024)

// ---------------- workspace layout (bytes) ----------------
#define OFF_XB    0ul          // bf16 x      [512][64][256]   = 16 MiB
#define OFF_WXP   16777216ul   // bf16 Wx^T   [4096][256]      =  2 MiB   (packed [col][k])
#define OFF_WHP   18874368ul   // bf16 Wh^T   [4096][1024]     =  8 MiB   (packed [col][k])
#define OFF_BIAS  27262976ul   // f32 bx+bh   [4096]
#define OFF_HBUF  27279360ul   // bf16 h      [2][64][1024]    = 256 KiB (double buffer)
#define OFF_FLAGS 27541504ul   // int flags   [128][16]        (one flag per 64B line)

typedef __attribute__((ext_vector_type(8))) __bf16 bf16x8;
typedef __attribute__((ext_vector_type(4))) float  floatx4;

struct KPtrs { const float* p[17]; };

__device__ __forceinline__ unsigned short f2bf(float f) {  // fp32 -> bf16 RTN-even
  unsigned int u = __float_as_uint(f);
  u += 0x7fffu + ((u >> 16) & 1u);
  return (unsigned short)(u >> 16);
}

__device__ __forceinline__ bf16x8 ld16(const unsigned short* p) {
  return *(const bf16x8*)p;   // cached global_load_dwordx4
}

// system-scope (L2-bypassing, always-fresh) 16B load as 2x atomic dwordx2
__device__ __forceinline__ bf16x8 ldsys16(const unsigned short* p) {
  unsigned long long a =
      __hip_atomic_load((const unsigned long long*)p,       __ATOMIC_RELAXED, __HIP_MEMORY_SCOPE_SYSTEM);
  unsigned long long b =
      __hip_atomic_load((const unsigned long long*)(p + 4), __ATOMIC_RELAXED, __HIP_MEMORY_SCOPE_SYSTEM);
  unsigned long long arr[2] = {a, b};
  bf16x8 r;
  __builtin_memcpy(&r, arr, 16);
  return r;
}

__device__ __forceinline__ float fsig(float x) {
  return __builtin_amdgcn_rcpf(1.f + __expf(-x));
}
__device__ __forceinline__ float ftanh(float x) {
  return 1.f - 2.f * __builtin_amdgcn_rcpf(1.f + __expf(2.f * x));
}

// ---------------- pack/convert + state init ----------------
__global__ void pack_kernel(KPtrs P, unsigned char* ws) {
  unsigned short* xb   = (unsigned short*)(ws + OFF_XB);
  unsigned short* wxp  = (unsigned short*)(ws + OFF_WXP);
  unsigned short* whp  = (unsigned short*)(ws + OFF_WHP);
  float*          bias = (float*)(ws + OFF_BIAS);
  unsigned int*   hb32 = (unsigned int*)(ws + OFF_HBUF);
  int*            flg  = (int*)(ws + OFF_FLAGS);
  const float* x = P.p[0];

  const long tid = (long)blockIdx.x * blockDim.x + threadIdx.x;
  const long nth = (long)gridDim.x * blockDim.x;

  for (long e = tid; e < 8388608l; e += nth)       // x -> bf16, same flat layout
    xb[e] = f2bf(x[e]);
  for (long e = tid; e < 1048576l; e += nth) {     // Wx packed [col][k]
    int c = (int)(e >> 8), i = (int)(e & 255);
    int gg = c >> 10, j = c & 1023;
    wxp[e] = f2bf(P.p[1 + 4 * gg][i * 1024 + j]);  // W1,W3,W5,W7
  }
  for (long e = tid; e < 4194304l; e += nth) {     // Wh packed [col][k]
    int c = (int)(e >> 10), k = (int)(e & 1023);
    int gg = c >> 10, j = c & 1023;
    whp[e] = f2bf(P.p[3 + 4 * gg][k * 1024 + j]);  // W2,W4,W6,W8
  }
  for (long e = tid; e < 4096l; e += nth) {        // bx + bh
    int gg = (int)(e >> 10), j = (int)(e & 1023);
    bias[e] = P.p[2 + 4 * gg][j] + P.p[4 + 4 * gg][j];
  }
  // h double buffer = 0 (system stores: visible to L2-bypassing readers)
  for (long e = tid; e < 65536l; e += nth)
    __hip_atomic_store(&hb32[e], 0u, __ATOMIC_RELAXED, __HIP_MEMORY_SCOPE_SYSTEM);
  // flags = -1  (h_{-1} ready)
  for (long e = tid; e < 128l; e += nth)
    __hip_atomic_store(&flg[e * 16], -1, __ATOMIC_RELAXED, __HIP_MEMORY_SCOPE_SYSTEM);
}

// ---------------- persistent fused LSTM ----------------
// 128 blocks = 2 batch-groups (32 batches) x 64 hidden-slices (16 units).
// Block (g,s): gates cols {gt*1024 + 16s..16s+15}, K split over 4 waves.
__global__ void __launch_bounds__(256, 1)
lstm_kernel(const unsigned char* __restrict__ ws, float* __restrict__ out) {
  const unsigned short* xb   = (const unsigned short*)(ws + OFF_XB);
  const unsigned short* wxp  = (const unsigned short*)(ws + OFF_WXP);
  const unsigned short* whp  = (const unsigned short*)(ws + OFF_WHP);
  const float*          bias = (const float*)(ws + OFF_BIAS);
  unsigned short*       hbuf = (unsigned short*)(ws + OFF_HBUF);
  int*                  flg  = (int*)(ws + OFF_FLAGS);

  const int tid = threadIdx.x;
  const int wv = tid >> 6, lane = tid & 63;
  const int r = lane & 15, q = lane >> 4;          // MFMA frag row/col + k-quad
  const int s = blockIdx.x & 63, g = blockIdx.x >> 6;

  __shared__ float pc[4][8][64][4];                // [wave][tile][lane][reg] partials, 32 KiB

  // B-operand bases (packed [col][k], lane -> col = lane&15, k-quad offset q*8)
  const unsigned short* wh_b[4];
  const unsigned short* wx_b[4];
#pragma unroll
  for (int nt = 0; nt < 4; ++nt) {
    const int c = nt * 1024 + s * 16 + r;
    wh_b[nt] = whp + (long)c * 1024 + q * 8;
    wx_b[nt] = wxp + (long)c * 256 + q * 8;
  }
  const unsigned short* xa0 = xb + ((long)g * 32 + r) * 256 + q * 8;

  int* myf = flg + (g * 64 + wv * 16 + (lane & 15)) * 16;  // this wave's 16 k-slices

  const int ej = tid & 15, ebp = tid >> 4;                 // epilogue: (batch=ebp[+16], j=ej)
  const int lidx = ej | ((ebp >> 2) << 4), rg = ebp & 3;   // C-frag: col=lane&15, row=quad*4+reg
  float cst[2] = {0.f, 0.f};                               // c-state, 2 batches/thread

  for (int t = 0; t < 512; ++t) {
    floatx4 acc[2][4];
#pragma unroll
    for (int mt = 0; mt < 2; ++mt)
#pragma unroll
      for (int nt = 0; nt < 4; ++nt) acc[mt][nt] = (floatx4){0.f, 0.f, 0.f, 0.f};

    // ---- x-side K (no dependency: runs while producers finish; hides poll) ----
    const unsigned short* xaT = xa0 + (long)t * (64 * 256);
#pragma unroll
    for (int kk = 0; kk < 2; ++kk) {
      const int k0 = wv * 64 + kk * 32;
      bf16x8 a0 = ld16(xaT + k0);
      bf16x8 a1 = ld16(xaT + 16 * 256 + k0);
#pragma unroll
      for (int nt = 0; nt < 4; ++nt) {
        bf16x8 b = ld16(wx_b[nt] + k0);
        acc[0][nt] = __builtin_amdgcn_mfma_f32_16x16x32_bf16(a0, b, acc[0][nt], 0, 0, 0);
        acc[1][nt] = __builtin_amdgcn_mfma_f32_16x16x32_bf16(a1, b, acc[1][nt], 0, 0, 0);
      }
    }

    // ---- wait for this wave's h_{t-1} slices ----
    while (true) {
      int fv = __hip_atomic_load(myf, __ATOMIC_RELAXED, __HIP_MEMORY_SCOPE_SYSTEM);
      if (__all(fv >= t - 1)) break;
      __builtin_amdgcn_s_sleep(1);
    }
    asm volatile("" ::: "memory");

    // ---- h-side K (system-scope loads: always coherent, L2 untouched) ----
    const unsigned short* ha =
        hbuf + (long)((t - 1) & 1) * 65536 + ((long)g * 32 + r) * 1024 + q * 8;
#pragma unroll 2
    for (int kk = 0; kk < 8; ++kk) {
      const int k0 = wv * 256 + kk * 32;
      bf16x8 a0 = ldsys16(ha + k0);
      bf16x8 a1 = ldsys16(ha + 16 * 1024 + k0);
#pragma unroll
      for (int nt = 0; nt < 4; ++nt) {
        bf16x8 b = ld16(wh_b[nt] + k0);
        acc[0][nt] = __builtin_amdgcn_mfma_f32_16x16x32_bf16(a0, b, acc[0][nt], 0, 0, 0);
        acc[1][nt] = __builtin_amdgcn_mfma_f32_16x16x32_bf16(a1, b, acc[1][nt], 0, 0, 0);
      }
    }

    // ---- cross-wave K reduction via LDS ----
#pragma unroll
    for (int mt = 0; mt < 2; ++mt)
#pragma unroll
      for (int nt = 0; nt < 4; ++nt)
        *(floatx4*)(&pc[wv][mt * 4 + nt][lane][0]) = acc[mt][nt];
    __syncthreads();

    // ---- gates + state update: thread -> (batch ebp & ebp+16, hidden j=ej) ----
    float hv[2], cv[2];
#pragma unroll
    for (int e = 0; e < 2; ++e) {
      float gs[4];
#pragma unroll
      for (int gt = 0; gt < 4; ++gt) {
        float sv = bias[gt * 1024 + s * 16 + ej];
#pragma unroll
        for (int w2 = 0; w2 < 4; ++w2) sv += pc[w2][e * 4 + gt][lidx][rg];
        gs[gt] = sv;
      }
      const float f = fsig(gs[0]), ii = fsig(gs[1]), o = fsig(gs[2]);
      const float cd = ftanh(gs[3]);
      cst[e] = f * cst[e] + ii * cd;
      cv[e] = cst[e];
      hv[e] = o * ftanh(cst[e]);
    }

    // ---- emit h_seq (fp32) + h for consumers (bf16, system write-through) ----
#pragma unroll
    for (int e = 0; e < 2; ++e) {
      const int bl = e * 16 + ebp;
      const long oidx = (long)t * 65536 + (g * 32 + bl) * 1024 + s * 16 + ej;
      out[oidx] = hv[e];
      if (t == 511) {
        out[33554432l + (g * 32 + bl) * 1024 + s * 16 + ej] = hv[e];
        out[33619968l + (g * 32 + bl) * 1024 + s * 16 + ej] = cv[e];
      }
      unsigned short hb = f2bf(hv[e]);
      unsigned short nb = (unsigned short)__shfl_xor((int)hb, 1, 64);
      if ((ej & 1) == 0) {   // pair 2 bf16 -> one u32 system store
        unsigned int pv = (unsigned int)hb | ((unsigned int)nb << 16);
        unsigned int* hp = (unsigned int*)(hbuf + (long)(t & 1) * 65536 +
                                           (g * 32 + bl) * 1024 + s * 16 + ej);
        __hip_atomic_store(hp, pv, __ATOMIC_RELAXED, __HIP_MEMORY_SCOPE_SYSTEM);
      }
    }
    __syncthreads();  // all h stores drained (vmcnt0 before barrier); also guards LDS reuse
    if (tid == 0)     // publish slice s of h_t
      __hip_atomic_store(&flg[(g * 64 + s) * 16], t, __ATOMIC_RELAXED, __HIP_MEMORY_SCOPE_SYSTEM);
  }
}

extern "C" void kernel_launch(void* const* d_in, const int* in_sizes, int n_in,
                              void* d_out, int out_size, void* d_ws, size_t ws_size,
                              hipStream_t stream) {
  (void)in_sizes; (void)n_in; (void)out_size; (void)ws_size;
  KPtrs P;
  for (int i = 0; i < 17; ++i) P.p[i] = (const float*)d_in[i];
  pack_kernel<<<dim3(2048), dim3(256), 0, stream>>>(P, (unsigned char*)d_ws);
  lstm_kernel<<<dim3(128), dim3(256), 0, stream>>>((const unsigned char*)d_ws, (float*)d_out);
}

// Round 3
// 4798.819 us; speedup vs baseline: 1.2206x; 1.2206x over previous
//
#include <hip/hip_runtime.h>

// ---------------- problem constants ----------------
// S=512 seq, B=64 batch, I=256 in, H=1024 hidden, 4H=4096 gates
// Wx = [W1 W3 W5 W7] (input side), Wh = [W2 W4 W6 W8] (hidden side)
// out: h_seq (512,64,1024) fp32, then h_final (64,1024), c_final (64,1024)

// ---------------- workspace layout (bytes) ----------------
#define OFF_XB    0ul          // bf16 x      [512][64][256]   = 16 MiB
#define OFF_WXP   16777216ul   // bf16 Wx^T   [4096][256]      =  2 MiB (packed [col][k])
#define OFF_WHP   18874368ul   // bf16 Wh^T   [4096][1024]     =  8 MiB (packed [col][k])
#define OFF_BIAS  27262976ul   // f32 bx+bh   [4096]
#define OFF_HBUF  27279360ul   // bf16 h      [2][64][1024]    = 256 KiB double buffer
#define OFF_CTR   27541504ul   // int counters: 8 lines, stride 1024 B

typedef __attribute__((ext_vector_type(8))) __bf16 bf16x8;
typedef __attribute__((ext_vector_type(4))) float  floatx4;

struct KPtrs { const float* p[17]; };

__device__ __forceinline__ unsigned short f2bf(float f) {  // fp32 -> bf16 RTN-even
  unsigned int u = __float_as_uint(f);
  u += 0x7fffu + ((u >> 16) & 1u);
  return (unsigned short)(u >> 16);
}

__device__ __forceinline__ bf16x8 ld16(const unsigned short* p) {
  return *(const bf16x8*)p;   // cached global_load_dwordx4
}

__device__ __forceinline__ float fsig(float x) {
  return __builtin_amdgcn_rcpf(1.f + __expf(-x));
}
__device__ __forceinline__ float ftanh(float x) {
  return 1.f - 2.f * __builtin_amdgcn_rcpf(1.f + __expf(2.f * x));
}

// ---------------- pack/convert + state init ----------------
__global__ void pack_kernel(KPtrs P, unsigned char* ws) {
  unsigned short* xb   = (unsigned short*)(ws + OFF_XB);
  unsigned short* wxp  = (unsigned short*)(ws + OFF_WXP);
  unsigned short* whp  = (unsigned short*)(ws + OFF_WHP);
  float*          bias = (float*)(ws + OFF_BIAS);
  unsigned int*   hb32 = (unsigned int*)(ws + OFF_HBUF);
  int*            ctr  = (int*)(ws + OFF_CTR);
  const float* x = P.p[0];

  const long tid = (long)blockIdx.x * blockDim.x + threadIdx.x;
  const long nth = (long)gridDim.x * blockDim.x;

  for (long e = tid; e < 8388608l; e += nth)       // x -> bf16, same flat layout
    xb[e] = f2bf(x[e]);
  for (long e = tid; e < 1048576l; e += nth) {     // Wx packed [col][k]
    int c = (int)(e >> 8), i = (int)(e & 255);
    int gg = c >> 10, j = c & 1023;
    wxp[e] = f2bf(P.p[1 + 4 * gg][i * 1024 + j]);  // W1,W3,W5,W7
  }
  for (long e = tid; e < 4194304l; e += nth) {     // Wh packed [col][k]
    int c = (int)(e >> 10), k = (int)(e & 1023);
    int gg = c >> 10, j = c & 1023;
    whp[e] = f2bf(P.p[3 + 4 * gg][k * 1024 + j]);  // W2,W4,W6,W8
  }
  for (long e = tid; e < 4096l; e += nth) {        // bx + bh
    int gg = (int)(e >> 10), j = (int)(e & 1023);
    bias[e] = P.p[2 + 4 * gg][j] + P.p[4 + 4 * gg][j];
  }
  // h double buffer = 0 (L2-bypassing stores: immediately at coherence point)
  for (long e = tid; e < 65536l; e += nth)
    __hip_atomic_store(&hb32[e], 0u, __ATOMIC_RELAXED, __HIP_MEMORY_SCOPE_AGENT);
  // counters = 0  (8 lines x 256 ints covers the 8 KiB region)
  for (long e = tid; e < 2048l; e += nth)
    __hip_atomic_store(&ctr[e], 0, __ATOMIC_RELAXED, __HIP_MEMORY_SCOPE_AGENT);
}

// ---------------- persistent fused LSTM ----------------
// 128 blocks = 2 batch-groups (32 batches) x 64 hidden-slices (16 units).
// Block (g,s): gate cols {gt*1024 + 16s .. +15}, K split over 4 waves.
// Wh/Wx fragments register-resident (immune to the per-step L2 invalidate).
__global__ void __launch_bounds__(256, 1)
lstm_kernel(const unsigned char* __restrict__ ws, float* __restrict__ out) {
  const unsigned short* xb   = (const unsigned short*)(ws + OFF_XB);
  const unsigned short* wxp  = (const unsigned short*)(ws + OFF_WXP);
  const unsigned short* whp  = (const unsigned short*)(ws + OFF_WHP);
  const float*          bias = (const float*)(ws + OFF_BIAS);
  unsigned short*       hbuf = (unsigned short*)(ws + OFF_HBUF);
  int*                  ctr  = (int*)(ws + OFF_CTR);

  const int tid = threadIdx.x;
  const int wv = tid >> 6, lane = tid & 63;
  const int r = lane & 15, q = lane >> 4;          // MFMA frag row + k-quad
  const int s = blockIdx.x & 63, g = blockIdx.x >> 6;

  __shared__ float pc[4][8][64][4];                // [wave][tile][lane][reg], 32 KiB

  // ---- preload weights into registers (loop-invariant) ----
  bf16x8 whf[4][8];   // [nt][kk]  128 VGPR
  bf16x8 wxf[4][2];   // [nt][kk]   32 VGPR
#pragma unroll
  for (int nt = 0; nt < 4; ++nt) {
    const int c = nt * 1024 + s * 16 + r;
    const unsigned short* whb = whp + (long)c * 1024 + q * 8;
    const unsigned short* wxb = wxp + (long)c * 256 + q * 8;
#pragma unroll
    for (int kk = 0; kk < 8; ++kk) whf[nt][kk] = ld16(whb + wv * 256 + kk * 32);
#pragma unroll
    for (int kk = 0; kk < 2; ++kk) wxf[nt][kk] = ld16(wxb + wv * 64 + kk * 32);
  }

  const unsigned short* xa0 = xb + ((long)g * 32 + r) * 256 + q * 8;

  // epilogue mapping: thread -> (batches ebp, ebp+16 ; hidden j = ej)
  const int ej = tid & 15, ebp = tid >> 4;
  const int lidx = ej | ((ebp >> 2) << 4), rg = ebp & 3;   // C-frag coords
  float bs[4];
#pragma unroll
  for (int gt = 0; gt < 4; ++gt) bs[gt] = bias[gt * 1024 + s * 16 + ej];

  int* myctr = ctr + (blockIdx.x & 7) * 256;               // this block's add line
  float cst[2] = {0.f, 0.f};

  for (int t = 0; t < 512; ++t) {
    floatx4 acc[2][4];
#pragma unroll
    for (int mt = 0; mt < 2; ++mt)
#pragma unroll
      for (int nt = 0; nt < 4; ++nt) acc[mt][nt] = (floatx4){0.f, 0.f, 0.f, 0.f};

    // ---- x-side K (no dependency; overlaps producers + hides poll) ----
    const unsigned short* xaT = xa0 + (long)t * (64 * 256);
#pragma unroll
    for (int kk = 0; kk < 2; ++kk) {
      const int k0 = wv * 64 + kk * 32;
      bf16x8 a0 = ld16(xaT + k0);
      bf16x8 a1 = ld16(xaT + 16 * 256 + k0);
#pragma unroll
      for (int nt = 0; nt < 4; ++nt) {
        acc[0][nt] = __builtin_amdgcn_mfma_f32_16x16x32_bf16(a0, wxf[nt][kk], acc[0][nt], 0, 0, 0);
        acc[1][nt] = __builtin_amdgcn_mfma_f32_16x16x32_bf16(a1, wxf[nt][kk], acc[1][nt], 0, 0, 0);
      }
    }

    // ---- wait: all 128 blocks published h_{t-1} (total counter >= 128t) ----
    if (wv == 0 && t > 0) {
      const int need = 128 * t;
      while (true) {
        int v = (lane < 8)
            ? __hip_atomic_load(ctr + lane * 256, __ATOMIC_RELAXED, __HIP_MEMORY_SCOPE_AGENT)
            : 0;
        v += __shfl_xor(v, 1); v += __shfl_xor(v, 2); v += __shfl_xor(v, 4);
        if (__shfl(v, 0) >= need) break;
        __builtin_amdgcn_s_sleep(1);
      }
    }
    __syncthreads();
    // invalidate stale L1/L2 lines; h reads below are then plain cached loads
    __builtin_amdgcn_fence(__ATOMIC_ACQUIRE, "agent");

    // ---- h-side K (cached: one L3 fetch per XCD, L2 hits for the rest) ----
    const unsigned short* ha =
        hbuf + (long)((t - 1) & 1) * 65536 + ((long)g * 32 + r) * 1024 + q * 8;
#pragma unroll
    for (int kk = 0; kk < 8; ++kk) {
      const int k0 = wv * 256 + kk * 32;
      bf16x8 a0 = ld16(ha + k0);
      bf16x8 a1 = ld16(ha + 16 * 1024 + k0);
#pragma unroll
      for (int nt = 0; nt < 4; ++nt) {
        acc[0][nt] = __builtin_amdgcn_mfma_f32_16x16x32_bf16(a0, whf[nt][kk], acc[0][nt], 0, 0, 0);
        acc[1][nt] = __builtin_amdgcn_mfma_f32_16x16x32_bf16(a1, whf[nt][kk], acc[1][nt], 0, 0, 0);
      }
    }

    // ---- cross-wave K reduction via LDS ----
#pragma unroll
    for (int mt = 0; mt < 2; ++mt)
#pragma unroll
      for (int nt = 0; nt < 4; ++nt)
        *(floatx4*)(&pc[wv][mt * 4 + nt][lane][0]) = acc[mt][nt];
    __syncthreads();

    // ---- gates + state update ----
    float hv[2], cv[2];
#pragma unroll
    for (int e = 0; e < 2; ++e) {
      float gs[4];
#pragma unroll
      for (int gt = 0; gt < 4; ++gt) {
        float sv = bs[gt];
#pragma unroll
        for (int w2 = 0; w2 < 4; ++w2) sv += pc[w2][e * 4 + gt][lidx][rg];
        gs[gt] = sv;
      }
      const float f = fsig(gs[0]), ii = fsig(gs[1]), o = fsig(gs[2]);
      const float cd = ftanh(gs[3]);
      cst[e] = f * cst[e] + ii * cd;
      cv[e] = cst[e];
      hv[e] = o * ftanh(cst[e]);
    }

    // ---- publish h_t (bf16, L2-bypassing write-through) ----
    unsigned int hpair[2]; int emit = ((ej & 1) == 0);
#pragma unroll
    for (int e = 0; e < 2; ++e) {
      unsigned short hb = f2bf(hv[e]);
      unsigned short nb = (unsigned short)__shfl_xor((int)hb, 1, 64);
      hpair[e] = (unsigned int)hb | ((unsigned int)nb << 16);
      if (emit) {
        unsigned int* hp = (unsigned int*)(hbuf + (long)(t & 1) * 65536 +
                                           (g * 32 + e * 16 + ebp) * 1024 + s * 16 + ej);
        __hip_atomic_store(hp, hpair[e], __ATOMIC_RELAXED, __HIP_MEMORY_SCOPE_AGENT);
      }
    }
    __syncthreads();  // drain h stores (vmcnt 0) before the publish-add
    if (tid == 0)
      __hip_atomic_fetch_add(myctr, 1, __ATOMIC_RELEASE, __HIP_MEMORY_SCOPE_AGENT);

    // ---- h_seq / finals (off critical path; drain overlaps next step) ----
#pragma unroll
    for (int e = 0; e < 2; ++e) {
      const int bl = e * 16 + ebp;
      const long oidx = (long)t * 65536 + (g * 32 + bl) * 1024 + s * 16 + ej;
      __hip_atomic_store((unsigned int*)&out[oidx], __float_as_uint(hv[e]),
                         __ATOMIC_RELAXED, __HIP_MEMORY_SCOPE_AGENT);
      if (t == 511) {
        __hip_atomic_store((unsigned int*)&out[33554432l + (g * 32 + bl) * 1024 + s * 16 + ej],
                           __float_as_uint(hv[e]), __ATOMIC_RELAXED, __HIP_MEMORY_SCOPE_AGENT);
        __hip_atomic_store((unsigned int*)&out[33619968l + (g * 32 + bl) * 1024 + s * 16 + ej],
                           __float_as_uint(cv[e]), __ATOMIC_RELAXED, __HIP_MEMORY_SCOPE_AGENT);
      }
    }
  }
}

extern "C" void kernel_launch(void* const* d_in, const int* in_sizes, int n_in,
                              void* d_out, int out_size, void* d_ws, size_t ws_size,
                              hipStream_t stream) {
  (void)in_sizes; (void)n_in; (void)out_size; (void)ws_size;
  KPtrs P;
  for (int i = 0; i < 17; ++i) P.p[i] = (const float*)d_in[i];
  pack_kernel<<<dim3(2048), dim3(256), 0, stream>>>(P, (unsigned char*)d_ws);
  lstm_kernel<<<dim3(128), dim3(256), 0, stream>>>((const unsigned char*)d_ws, (float*)d_out);
}

// Round 4
// 3079.134 us; speedup vs baseline: 1.9023x; 1.5585x over previous
//
#include <hip/hip_runtime.h>

// ---------------- problem constants ----------------
// S=512 seq, B=64 batch, I=256 in, H=1024 hidden, 4H=4096 gates
// Wx = [W1 W3 W5 W7] (input side), Wh = [W2 W4 W6 W8] (hidden side)
// out: h_seq (512,64,1024) fp32, then h_final (64,1024), c_final (64,1024)

// ---------------- workspace layout (bytes) ----------------
#define OFF_XB    0ul          // bf16 x      [512][64][256]   = 16 MiB
#define OFF_WXP   16777216ul   // bf16 Wx^T   [4096][256]      =  2 MiB (packed [col][k])
#define OFF_WHP   18874368ul   // bf16 Wh^T   [4096][1024]     =  8 MiB (packed [col][k])
#define OFF_BIAS  27262976ul   // f32 bx+bh   [4096]
#define OFF_HBUF  27279360ul   // bf16 h      [2][64][1024]    = 256 KiB double buffer
#define OFF_FLG   27541504ul   // int flags   [128]  (plain UC stores, no RMW)

typedef __attribute__((ext_vector_type(8))) __bf16 bf16x8;
typedef __attribute__((ext_vector_type(4))) float  floatx4;

struct KPtrs { const float* p[17]; };

__device__ __forceinline__ unsigned short f2bf(float f) {  // fp32 -> bf16 RTN-even
  unsigned int u = __float_as_uint(f);
  u += 0x7fffu + ((u >> 16) & 1u);
  return (unsigned short)(u >> 16);
}

__device__ __forceinline__ bf16x8 ld16(const unsigned short* p) {
  return *(const bf16x8*)p;   // cached global_load_dwordx4
}

// L3-coherent (UC, L2-bypassing) 16B load as 2x relaxed u64 atomic loads
__device__ __forceinline__ bf16x8 ldsys16(const unsigned short* p) {
  unsigned long long a =
      __hip_atomic_load((const unsigned long long*)p,       __ATOMIC_RELAXED, __HIP_MEMORY_SCOPE_AGENT);
  unsigned long long b =
      __hip_atomic_load((const unsigned long long*)(p + 4), __ATOMIC_RELAXED, __HIP_MEMORY_SCOPE_AGENT);
  unsigned long long arr[2] = {a, b};
  bf16x8 r;
  __builtin_memcpy(&r, arr, 16);
  return r;
}

__device__ __forceinline__ float fsig(float x) {
  return __builtin_amdgcn_rcpf(1.f + __expf(-x));
}
__device__ __forceinline__ float ftanh(float x) {
  return 1.f - 2.f * __builtin_amdgcn_rcpf(1.f + __expf(2.f * x));
}

// ---------------- pack/convert + state init ----------------
__global__ void pack_kernel(KPtrs P, unsigned char* ws) {
  unsigned short* xb   = (unsigned short*)(ws + OFF_XB);
  unsigned short* wxp  = (unsigned short*)(ws + OFF_WXP);
  unsigned short* whp  = (unsigned short*)(ws + OFF_WHP);
  float*          bias = (float*)(ws + OFF_BIAS);
  unsigned int*   hb32 = (unsigned int*)(ws + OFF_HBUF);
  int*            flg  = (int*)(ws + OFF_FLG);
  const float* x = P.p[0];

  const long tid = (long)blockIdx.x * blockDim.x + threadIdx.x;
  const long nth = (long)gridDim.x * blockDim.x;

  for (long e = tid; e < 8388608l; e += nth)       // x -> bf16, same flat layout
    xb[e] = f2bf(x[e]);
  for (long e = tid; e < 1048576l; e += nth) {     // Wx packed [col][k]
    int c = (int)(e >> 8), i = (int)(e & 255);
    int gg = c >> 10, j = c & 1023;
    wxp[e] = f2bf(P.p[1 + 4 * gg][i * 1024 + j]);  // W1,W3,W5,W7
  }
  for (long e = tid; e < 4194304l; e += nth) {     // Wh packed [col][k]
    int c = (int)(e >> 10), k = (int)(e & 1023);
    int gg = c >> 10, j = c & 1023;
    whp[e] = f2bf(P.p[3 + 4 * gg][k * 1024 + j]);  // W2,W4,W6,W8
  }
  for (long e = tid; e < 4096l; e += nth) {        // bx + bh
    int gg = (int)(e >> 10), j = (int)(e & 1023);
    bias[e] = P.p[2 + 4 * gg][j] + P.p[4 + 4 * gg][j];
  }
  // h double buffer = 0 (UC stores: land at the L3 coherence point)
  for (long e = tid; e < 65536l; e += nth)
    __hip_atomic_store(&hb32[e], 0u, __ATOMIC_RELAXED, __HIP_MEMORY_SCOPE_AGENT);
  // flags = -1  (h_{-1} ready)
  for (long e = tid; e < 128l; e += nth)
    __hip_atomic_store(&flg[e], -1, __ATOMIC_RELAXED, __HIP_MEMORY_SCOPE_AGENT);
}

// ---------------- persistent fused LSTM ----------------
// 128 blocks = 2 batch-groups (32 batches) x 64 hidden-slices (16 units).
// Block (g,s): gate cols {gt*1024 + 16s .. +15}, K split over 4 waves.
// NO fences, NO atomic RMW in the hot loop: h + flags are UC (L3-coherent);
// x / weights / bias / out are normal cached (L2 stays warm all 512 steps).
__global__ void __launch_bounds__(256, 1)
lstm_kernel(const unsigned char* __restrict__ ws, float* __restrict__ out) {
  const unsigned short* xb   = (const unsigned short*)(ws + OFF_XB);
  const unsigned short* wxp  = (const unsigned short*)(ws + OFF_WXP);
  const unsigned short* whp  = (const unsigned short*)(ws + OFF_WHP);
  const float*          bias = (const float*)(ws + OFF_BIAS);
  unsigned short*       hbuf = (unsigned short*)(ws + OFF_HBUF);
  int*                  flg  = (int*)(ws + OFF_FLG);

  const int tid = threadIdx.x;
  const int wv = tid >> 6, lane = tid & 63;
  const int r = lane & 15, q = lane >> 4;          // MFMA frag row + k-quad
  const int s = blockIdx.x & 63, g = blockIdx.x >> 6;

  __shared__ float pc[4][8][64][4];                // [wave][tile][lane][reg], 32 KiB

  // ---- preload weights into registers (loop-invariant) ----
  bf16x8 whf[4][8];   // [nt][kk]  128 VGPR
  bf16x8 wxf[4][2];   // [nt][kk]   32 VGPR
#pragma unroll
  for (int nt = 0; nt < 4; ++nt) {
    const int c = nt * 1024 + s * 16 + r;
    const unsigned short* whb = whp + (long)c * 1024 + q * 8;
    const unsigned short* wxb = wxp + (long)c * 256 + q * 8;
#pragma unroll
    for (int kk = 0; kk < 8; ++kk) whf[nt][kk] = ld16(whb + wv * 256 + kk * 32);
#pragma unroll
    for (int kk = 0; kk < 2; ++kk) wxf[nt][kk] = ld16(wxb + wv * 64 + kk * 32);
  }

  const unsigned short* xa0 = xb + ((long)g * 32 + r) * 256 + q * 8;

  // epilogue mapping: thread -> (batches ebp, ebp+16 ; hidden j = ej)
  const int ej = tid & 15, ebp = tid >> 4;
  const int lidx = ej | ((ebp >> 2) << 4), rg = ebp & 3;   // C-frag coords
  float bs[4];
#pragma unroll
  for (int gt = 0; gt < 4; ++gt) bs[gt] = bias[gt * 1024 + s * 16 + ej];

  const unsigned long long* fl64 = (const unsigned long long*)flg;
  float cst[2] = {0.f, 0.f};

  for (int t = 0; t < 512; ++t) {
    floatx4 acc[2][4];
#pragma unroll
    for (int mt = 0; mt < 2; ++mt)
#pragma unroll
      for (int nt = 0; nt < 4; ++nt) acc[mt][nt] = (floatx4){0.f, 0.f, 0.f, 0.f};

    // ---- x-side K (no dependency; overlaps producers + hides poll) ----
    const unsigned short* xaT = xa0 + (long)t * (64 * 256);
#pragma unroll
    for (int kk = 0; kk < 2; ++kk) {
      const int k0 = wv * 64 + kk * 32;
      bf16x8 a0 = ld16(xaT + k0);
      bf16x8 a1 = ld16(xaT + 16 * 256 + k0);
#pragma unroll
      for (int nt = 0; nt < 4; ++nt) {
        acc[0][nt] = __builtin_amdgcn_mfma_f32_16x16x32_bf16(a0, wxf[nt][kk], acc[0][nt], 0, 0, 0);
        acc[1][nt] = __builtin_amdgcn_mfma_f32_16x16x32_bf16(a1, wxf[nt][kk], acc[1][nt], 0, 0, 0);
      }
    }

    // ---- wait: all 128 flags >= t-1 (each lane checks 2 flags; no barrier) ----
    {
      const int need = t - 1;
      while (true) {
        unsigned long long fv =
            __hip_atomic_load(&fl64[lane], __ATOMIC_RELAXED, __HIP_MEMORY_SCOPE_AGENT);
        bool ok = ((int)(unsigned int)fv >= need) && ((int)(unsigned int)(fv >> 32) >= need);
        if (__all(ok)) break;
        __builtin_amdgcn_s_sleep(1);
      }
    }
    asm volatile("" ::: "memory");

    // ---- h-side K (UC loads: L3-coherent, never stale, L2 untouched) ----
    const unsigned short* ha =
        hbuf + (long)((t - 1) & 1) * 65536 + ((long)g * 32 + r) * 1024 + q * 8;
#pragma unroll
    for (int kk = 0; kk < 8; ++kk) {
      const int k0 = wv * 256 + kk * 32;
      bf16x8 a0 = ldsys16(ha + k0);
      bf16x8 a1 = ldsys16(ha + 16 * 1024 + k0);
#pragma unroll
      for (int nt = 0; nt < 4; ++nt) {
        acc[0][nt] = __builtin_amdgcn_mfma_f32_16x16x32_bf16(a0, whf[nt][kk], acc[0][nt], 0, 0, 0);
        acc[1][nt] = __builtin_amdgcn_mfma_f32_16x16x32_bf16(a1, whf[nt][kk], acc[1][nt], 0, 0, 0);
      }
    }

    // ---- cross-wave K reduction via LDS ----
#pragma unroll
    for (int mt = 0; mt < 2; ++mt)
#pragma unroll
      for (int nt = 0; nt < 4; ++nt)
        *(floatx4*)(&pc[wv][mt * 4 + nt][lane][0]) = acc[mt][nt];
    __syncthreads();

    // ---- gates + state update ----
    float hv[2], cv[2];
#pragma unroll
    for (int e = 0; e < 2; ++e) {
      float gs[4];
#pragma unroll
      for (int gt = 0; gt < 4; ++gt) {
        float sv = bs[gt];
#pragma unroll
        for (int w2 = 0; w2 < 4; ++w2) sv += pc[w2][e * 4 + gt][lidx][rg];
        gs[gt] = sv;
      }
      const float f = fsig(gs[0]), ii = fsig(gs[1]), o = fsig(gs[2]);
      const float cd = ftanh(gs[3]);
      cst[e] = f * cst[e] + ii * cd;
      cv[e] = cst[e];
      hv[e] = o * ftanh(cst[e]);
    }

    // ---- publish h_t (bf16, UC write-through to L3) ----
    int emit = ((ej & 1) == 0);
#pragma unroll
    for (int e = 0; e < 2; ++e) {
      unsigned short hb = f2bf(hv[e]);
      unsigned short nb = (unsigned short)__shfl_xor((int)hb, 1, 64);
      if (emit) {
        unsigned int pv = (unsigned int)hb | ((unsigned int)nb << 16);
        unsigned int* hp = (unsigned int*)(hbuf + (long)(t & 1) * 65536 +
                                           (g * 32 + e * 16 + ebp) * 1024 + s * 16 + ej);
        __hip_atomic_store(hp, pv, __ATOMIC_RELAXED, __HIP_MEMORY_SCOPE_AGENT);
      }
    }
    __syncthreads();  // vmcnt(0): all h stores acked at L3 before flag store
    if (tid == 0)     // plain UC flag store — no RMW, no fence
      __hip_atomic_store(&flg[blockIdx.x], t, __ATOMIC_RELAXED, __HIP_MEMORY_SCOPE_AGENT);

    // ---- h_seq / finals: normal cached stores (write-back; flushed at kernel end) ----
#pragma unroll
    for (int e = 0; e < 2; ++e) {
      const int bl = e * 16 + ebp;
      const long oidx = (long)t * 65536 + (g * 32 + bl) * 1024 + s * 16 + ej;
      out[oidx] = hv[e];
      if (t == 511) {
        out[33554432l + (g * 32 + bl) * 1024 + s * 16 + ej] = hv[e];
        out[33619968l + (g * 32 + bl) * 1024 + s * 16 + ej] = cv[e];
      }
    }
  }
}

extern "C" void kernel_launch(void* const* d_in, const int* in_sizes, int n_in,
                              void* d_out, int out_size, void* d_ws, size_t ws_size,
                              hipStream_t stream) {
  (void)in_sizes; (void)n_in; (void)out_size; (void)ws_size;
  KPtrs P;
  for (int i = 0; i < 17; ++i) P.p[i] = (const float*)d_in[i];
  pack_kernel<<<dim3(2048), dim3(256), 0, stream>>>(P, (unsigned char*)d_ws);
  lstm_kernel<<<dim3(128), dim3(256), 0, stream>>>((const unsigned char*)d_ws, (float*)d_out);
}